// Round 4
// baseline (1466.392 us; speedup 1.0000x reference)
//
#include <hip/hip_runtime.h>
#include <cstdint>
#include <cstddef>

typedef short bf16x8 __attribute__((ext_vector_type(8)));
typedef float floatx4 __attribute__((ext_vector_type(4)));
typedef unsigned short ushort4v __attribute__((ext_vector_type(4)));

#define LN_EPS 1e-5f
#define ATTN_EPS 1e-8f
#define NCHUNK 32

__device__ __forceinline__ unsigned short f2bf(float f) {
    unsigned int u = __float_as_uint(f);
    u += 0x7fffu + ((u >> 16) & 1u);
    return (unsigned short)(u >> 16);
}

__device__ __forceinline__ void load_lds16(const void* gp, void* lp) {
    __builtin_amdgcn_global_load_lds(
        (__attribute__((address_space(1))) void*)gp,
        (__attribute__((address_space(3))) void*)lp,
        16, 0, 0);
}

// ---------------- LayerNorm over rows of 512, one wave per row ----------------
template<bool OUT_BF16>
__global__ __launch_bounds__(256) void ln512_kernel(
        const float* __restrict__ x, const float* __restrict__ g, const float* __restrict__ b,
        void* __restrict__ out, int total_rows, int data_rows, float outscale) {
    int row = blockIdx.x * 4 + (threadIdx.x >> 6);
    int lane = threadIdx.x & 63;
    if (row >= total_rows) return;
    int rr = row < data_rows ? row : data_rows - 1;
    const float4* xr = (const float4*)(x + (size_t)rr * 512);
    float4 a0 = xr[lane];
    float4 a1 = xr[lane + 64];
    float s  = a0.x + a0.y + a0.z + a0.w + a1.x + a1.y + a1.z + a1.w;
    float ss = a0.x*a0.x + a0.y*a0.y + a0.z*a0.z + a0.w*a0.w
             + a1.x*a1.x + a1.y*a1.y + a1.z*a1.z + a1.w*a1.w;
    #pragma unroll
    for (int off = 32; off > 0; off >>= 1) {
        s  += __shfl_xor(s, off, 64);
        ss += __shfl_xor(ss, off, 64);
    }
    float mu = s * (1.0f / 512.0f);
    float var = ss * (1.0f / 512.0f) - mu * mu;
    float rstd = rsqrtf(var + LN_EPS);
    float4 g0 = ((const float4*)g)[lane];
    float4 g1 = ((const float4*)g)[lane + 64];
    float4 b0 = ((const float4*)b)[lane];
    float4 b1 = ((const float4*)b)[lane + 64];
    float y[8];
    y[0] = ((a0.x - mu) * rstd * g0.x + b0.x) * outscale;
    y[1] = ((a0.y - mu) * rstd * g0.y + b0.y) * outscale;
    y[2] = ((a0.z - mu) * rstd * g0.z + b0.z) * outscale;
    y[3] = ((a0.w - mu) * rstd * g0.w + b0.w) * outscale;
    y[4] = ((a1.x - mu) * rstd * g1.x + b1.x) * outscale;
    y[5] = ((a1.y - mu) * rstd * g1.y + b1.y) * outscale;
    y[6] = ((a1.z - mu) * rstd * g1.z + b1.z) * outscale;
    y[7] = ((a1.w - mu) * rstd * g1.w + b1.w) * outscale;
    if (OUT_BF16) {
        unsigned short* orow = (unsigned short*)out + (size_t)row * 512;
        ushort4v o0, o1;
        o0.x = f2bf(y[0]); o0.y = f2bf(y[1]); o0.z = f2bf(y[2]); o0.w = f2bf(y[3]);
        o1.x = f2bf(y[4]); o1.y = f2bf(y[5]); o1.z = f2bf(y[6]); o1.w = f2bf(y[7]);
        *(ushort4v*)(orow + lane * 4) = o0;
        *(ushort4v*)(orow + 256 + lane * 4) = o1;
    } else {
        float* orow = (float*)out + (size_t)row * 512;
        *(float4*)(orow + lane * 4) = make_float4(y[0], y[1], y[2], y[3]);
        *(float4*)(orow + 256 + lane * 4) = make_float4(y[4], y[5], y[6], y[7]);
    }
}

// --------- pack W = [Wk|Wv] transposed to [N=1024][K=512] bf16 ----------
__global__ __launch_bounds__(256) void prep_wt(const float* __restrict__ Wk,
                                               const float* __restrict__ Wv,
                                               unsigned short* __restrict__ wt) {
    int idx = blockIdx.x * 256 + threadIdx.x;
    if (idx >= 1024 * 512) return;
    int n = idx >> 9, kk = idx & 511;
    float v = (n < 512) ? Wk[(size_t)kk * 512 + n] : Wv[(size_t)kk * 512 + (n - 512)];
    wt[idx] = f2bf(v);
}

// --------- transpose-convert: in [R][C] fp32 -> out [C][R] bf16 ----------
__global__ __launch_bounds__(256) void transpose_bf(const float* __restrict__ in,
                                                    unsigned short* __restrict__ out,
                                                    int R, int C) {
    __shared__ float tile[32][33];
    int bx = blockIdx.x * 32, by = blockIdx.y * 32;
    int tx = threadIdx.x & 31, ty = threadIdx.x >> 5;
    #pragma unroll
    for (int i = 0; i < 32; i += 8)
        tile[ty + i][tx] = in[(size_t)(by + ty + i) * C + bx + tx];
    __syncthreads();
    #pragma unroll
    for (int i = 0; i < 32; i += 8)
        out[(size_t)(bx + ty + i) * R + by + tx] = f2bf(tile[tx][ty + i]);
}

__global__ __launch_bounds__(256) void conv_bf(const float* __restrict__ in,
                                               unsigned short* __restrict__ out, int n) {
    int i = blockIdx.x * 256 + threadIdx.x;
    if (i < n) out[i] = f2bf(in[i]);
}

__global__ __launch_bounds__(256) void conv_bf_rows(const float* __restrict__ in,
                                                    unsigned short* __restrict__ out,
                                                    int total, int data_rows) {
    int i = blockIdx.x * 256 + threadIdx.x;
    if (i >= total * 512) return;
    int row = i >> 9, d = i & 511;
    int rr = row < data_rows ? row : data_rows - 1;
    out[i] = f2bf(in[(size_t)rr * 512 + d]);
}

// ---------------- k/v projection GEMM: A via LDS, B direct-to-register ----------------
// 128x128 tile, BK=64, XOR-swizzled A staging, XCD-stripe grid swizzle.
__global__ __launch_bounds__(256) void kv_gemm(
        const unsigned short* __restrict__ xln, const unsigned short* __restrict__ wt,
        const float* __restrict__ bk, const float* __restrict__ bv,
        unsigned short* __restrict__ kout, unsigned short* __restrict__ vout) {
    __shared__ unsigned short As[128 * 64];
    const int t = threadIdx.x;
    const int lane = t & 63;
    const int w = t >> 6;
    const int wm = w >> 1, wn = w & 1;
    const int id = blockIdx.x;
    const int xcd = id & 7;
    const int slot = id >> 3;
    const int n0 = (slot & 7) * 128;
    const int m0 = (((slot >> 3) << 3) | xcd) * 128;
    const int quad = lane >> 4;
    const int l15 = lane & 15;
    const unsigned short* bp = wt + (size_t)(n0 + wn * 64 + l15) * 512 + quad * 8;
    floatx4 acc[4][4];
    #pragma unroll
    for (int i = 0; i < 4; ++i)
        #pragma unroll
        for (int j = 0; j < 4; ++j)
            #pragma unroll
            for (int r = 0; r < 4; ++r) acc[i][j][r] = 0.0f;

    for (int k0 = 0; k0 < 512; k0 += 64) {
        #pragma unroll
        for (int p = 0; p < 4; ++p) {
            const int s = p * 256 + t;          // 1024 chunks of 16B
            const int row = s >> 3;
            const int c = (s & 7) ^ (row & 7);  // swizzled source chunk
            const int ldsoff = (s - lane) * 16;
            load_lds16(xln + (size_t)(m0 + row) * 512 + k0 + c * 8, (char*)As + ldsoff);
        }
        // B fragments direct from global (L2-resident)
        bf16x8 bfr[2][4];
        #pragma unroll
        for (int h = 0; h < 2; ++h)
            #pragma unroll
            for (int j = 0; j < 4; ++j)
                bfr[h][j] = *(const bf16x8*)(bp + (size_t)j * 16 * 512 + k0 + h * 32);
        __builtin_amdgcn_s_waitcnt(0);
        __syncthreads();
        #pragma unroll
        for (int h = 0; h < 2; ++h) {
            bf16x8 af[4];
            #pragma unroll
            for (int i = 0; i < 4; ++i) {
                const int row = wm * 64 + i * 16 + l15;
                const int cp = ((h << 2) | quad) ^ (l15 & 7);
                af[i] = *(const bf16x8*)(As + row * 64 + cp * 8);
            }
            #pragma unroll
            for (int i = 0; i < 4; ++i)
                #pragma unroll
                for (int j = 0; j < 4; ++j)
                    acc[i][j] = __builtin_amdgcn_mfma_f32_16x16x32_bf16(af[i], bfr[h][j], acc[i][j], 0, 0, 0);
        }
        __syncthreads();
    }
    #pragma unroll
    for (int j = 0; j < 4; ++j) {
        const int n = n0 + wn * 64 + j * 16 + l15;
        const bool isk = (n < 512);
        const float bias = isk ? bk[n] : bv[n - 512];
        unsigned short* outp = isk ? kout : vout;
        const int nc = isk ? n : n - 512;
        #pragma unroll
        for (int i = 0; i < 4; ++i) {
            #pragma unroll
            for (int r = 0; r < 4; ++r) {
                const int m = m0 + wm * 64 + i * 16 + quad * 4 + r;
                outp[(size_t)m * 512 + nc] = f2bf(acc[i][j][r] + bias);
            }
        }
    }
}

// ---------------- direct-to-register MFMA GEMM (no LDS, no barriers) ----------------
// One wave per 64x64 C-tile. A bf16 [Mp][K], Bt bf16 [N][K]. K % 64 == 0.
// OUT_MODE: 0 = fp32 Cf, 1 = bf16 Cb, 2 = both.
template<bool BIAS, bool RELU, int OUT_MODE>
__device__ __forceinline__ void rgemm_core(
        const unsigned short* __restrict__ A, const unsigned short* __restrict__ Bt,
        const float* __restrict__ bias, float* __restrict__ Cf,
        unsigned short* __restrict__ Cb, int m0, int n0, int N, int K) {
    const int lane = threadIdx.x & 63;
    const int quad = lane >> 4, l15 = lane & 15;
    const unsigned short* ap = A  + (size_t)(m0 + l15) * K + quad * 8;
    const unsigned short* bp = Bt + (size_t)(n0 + l15) * K + quad * 8;
    floatx4 acc[4][4];
    #pragma unroll
    for (int i = 0; i < 4; ++i)
        #pragma unroll
        for (int j = 0; j < 4; ++j)
            #pragma unroll
            for (int r = 0; r < 4; ++r) acc[i][j][r] = 0.0f;

    bf16x8 a0[4], b0[4], a1[4], b1[4];
    #pragma unroll
    for (int i = 0; i < 4; ++i) {
        a0[i] = *(const bf16x8*)(ap + (size_t)i * 16 * K);
        b0[i] = *(const bf16x8*)(bp + (size_t)i * 16 * K);
    }
    for (int k0 = 0; k0 < K; k0 += 64) {
        #pragma unroll
        for (int i = 0; i < 4; ++i) {
            a1[i] = *(const bf16x8*)(ap + (size_t)i * 16 * K + k0 + 32);
            b1[i] = *(const bf16x8*)(bp + (size_t)i * 16 * K + k0 + 32);
        }
        #pragma unroll
        for (int i = 0; i < 4; ++i)
            #pragma unroll
            for (int j = 0; j < 4; ++j)
                acc[i][j] = __builtin_amdgcn_mfma_f32_16x16x32_bf16(a0[i], b0[j], acc[i][j], 0, 0, 0);
        const bool more = (k0 + 64) < K;
        if (more) {
            #pragma unroll
            for (int i = 0; i < 4; ++i) {
                a0[i] = *(const bf16x8*)(ap + (size_t)i * 16 * K + k0 + 64);
                b0[i] = *(const bf16x8*)(bp + (size_t)i * 16 * K + k0 + 64);
            }
        }
        #pragma unroll
        for (int i = 0; i < 4; ++i)
            #pragma unroll
            for (int j = 0; j < 4; ++j)
                acc[i][j] = __builtin_amdgcn_mfma_f32_16x16x32_bf16(a1[i], b1[j], acc[i][j], 0, 0, 0);
    }
    #pragma unroll
    for (int j = 0; j < 4; ++j) {
        const int n = n0 + j * 16 + l15;
        const float bb = BIAS ? bias[n] : 0.0f;
        #pragma unroll
        for (int i = 0; i < 4; ++i) {
            #pragma unroll
            for (int r = 0; r < 4; ++r) {
                const int m = m0 + i * 16 + quad * 4 + r;
                float v = acc[i][j][r] + bb;
                if (RELU) v = fmaxf(v, 0.0f);
                if (OUT_MODE == 0 || OUT_MODE == 2) Cf[(size_t)m * N + n] = v;
                if (OUT_MODE == 1 || OUT_MODE == 2) Cb[(size_t)m * N + n] = f2bf(v);
            }
        }
    }
}

template<bool BIAS, bool RELU, int OUT_MODE>
__global__ __launch_bounds__(64) void rgemm(
        const unsigned short* __restrict__ A, const unsigned short* __restrict__ Bt,
        const float* __restrict__ bias, float* __restrict__ Cf,
        unsigned short* __restrict__ Cb, int N, int K) {
    rgemm_core<BIAS, RELU, OUT_MODE>(A, Bt, bias, Cf, Cb,
                                     blockIdx.y * 64, blockIdx.x * 64, N, K);
}

// gi and gh in one launch (blockIdx.z selects)
__global__ __launch_bounds__(64) void gru_gemm(
        const unsigned short* __restrict__ upd, const unsigned short* __restrict__ slbf,
        const unsigned short* __restrict__ Wih, const unsigned short* __restrict__ Whh,
        const float* __restrict__ bih, const float* __restrict__ bhh,
        float* __restrict__ gi, float* __restrict__ gh) {
    if (blockIdx.z == 0)
        rgemm_core<true, false, 0>(upd, Wih, bih, gi, nullptr,
                                   blockIdx.y * 64, blockIdx.x * 64, 1536, 512);
    else
        rgemm_core<true, false, 0>(slbf, Whh, bhh, gh, nullptr,
                                   blockIdx.y * 64, blockIdx.x * 64, 1536, 512);
}

// ---------------- fused inverted attention ----------------
__global__ __launch_bounds__(256) void attn_kernel(
        const float* __restrict__ q, const unsigned short* __restrict__ kbf,
        const unsigned short* __restrict__ vbf,
        float* __restrict__ Up, float* __restrict__ rsp) {
    const int b = blockIdx.y;
    const int chunk = blockIdx.x;
    const int w = threadIdx.x >> 6, lane = threadIdx.x & 63;
    const int d0 = lane * 8;
    const int NPC = 4096 / NCHUNK;

    float qr[11][8];
    {
        const float* qb = q + (size_t)b * 11 * 512 + d0;
        #pragma unroll
        for (int s = 0; s < 11; ++s) {
            float4 q0 = *(const float4*)(qb + s * 512);
            float4 q1 = *(const float4*)(qb + s * 512 + 4);
            qr[s][0] = q0.x; qr[s][1] = q0.y; qr[s][2] = q0.z; qr[s][3] = q0.w;
            qr[s][4] = q1.x; qr[s][5] = q1.y; qr[s][6] = q1.z; qr[s][7] = q1.w;
        }
    }
    float U[11][8];
    float rs[11];
    #pragma unroll
    for (int s = 0; s < 11; ++s) {
        rs[s] = 0.f;
        #pragma unroll
        for (int j = 0; j < 8; ++j) U[s][j] = 0.f;
    }

    const size_t base = ((size_t)b * 4096 + (size_t)chunk * NPC) * 512 + d0;
    for (int nn = w; nn < NPC; nn += 4) {
        const unsigned short* kp = kbf + base + (size_t)nn * 512;
        const unsigned short* vp = vbf + base + (size_t)nn * 512;
        uint4 kr = *(const uint4*)kp;
        float kf[8];
        kf[0] = __uint_as_float(kr.x << 16); kf[1] = __uint_as_float(kr.x & 0xffff0000u);
        kf[2] = __uint_as_float(kr.y << 16); kf[3] = __uint_as_float(kr.y & 0xffff0000u);
        kf[4] = __uint_as_float(kr.z << 16); kf[5] = __uint_as_float(kr.z & 0xffff0000u);
        kf[6] = __uint_as_float(kr.w << 16); kf[7] = __uint_as_float(kr.w & 0xffff0000u);
        float l[11];
        #pragma unroll
        for (int s = 0; s < 11; ++s) {
            float p = kf[0] * qr[s][0];
            #pragma unroll
            for (int j = 1; j < 8; ++j) p = fmaf(kf[j], qr[s][j], p);
            l[s] = p;
        }
        #pragma unroll
        for (int off = 32; off > 0; off >>= 1)
            #pragma unroll
            for (int s = 0; s < 11; ++s) l[s] += __shfl_xor(l[s], off, 64);
        float mx = l[0];
        #pragma unroll
        for (int s = 1; s < 11; ++s) mx = fmaxf(mx, l[s]);
        float se = 0.f;
        #pragma unroll
        for (int s = 0; s < 11; ++s) { l[s] = __expf(l[s] - mx); se += l[s]; }
        float inv = 1.0f / se;
        uint4 vr = *(const uint4*)vp;
        float vf[8];
        vf[0] = __uint_as_float(vr.x << 16); vf[1] = __uint_as_float(vr.x & 0xffff0000u);
        vf[2] = __uint_as_float(vr.y << 16); vf[3] = __uint_as_float(vr.y & 0xffff0000u);
        vf[4] = __uint_as_float(vr.z << 16); vf[5] = __uint_as_float(vr.z & 0xffff0000u);
        vf[6] = __uint_as_float(vr.w << 16); vf[7] = __uint_as_float(vr.w & 0xffff0000u);
        #pragma unroll
        for (int s = 0; s < 11; ++s) {
            float a = l[s] * inv;
            rs[s] += a;
            #pragma unroll
            for (int j = 0; j < 8; ++j) U[s][j] = fmaf(a, vf[j], U[s][j]);
        }
    }
    __shared__ float Us[11 * 512];
    __shared__ float rss[11];
    for (int ph = 0; ph < 4; ++ph) {
        if (w == ph) {
            #pragma unroll
            for (int s = 0; s < 11; ++s) {
                #pragma unroll
                for (int j = 0; j < 8; ++j) {
                    if (ph == 0) Us[s * 512 + d0 + j] = U[s][j];
                    else         Us[s * 512 + d0 + j] += U[s][j];
                }
            }
            if (lane == 0) {
                #pragma unroll
                for (int s = 0; s < 11; ++s) {
                    if (ph == 0) rss[s] = rs[s]; else rss[s] += rs[s];
                }
            }
        }
        __syncthreads();
    }
    float* up = Up + ((size_t)b * NCHUNK + chunk) * 11 * 512;
    for (int idx = threadIdx.x; idx < 11 * 512; idx += 256) up[idx] = Us[idx];
    if (threadIdx.x < 11) rsp[((size_t)b * NCHUNK + chunk) * 11 + threadIdx.x] = rss[threadIdx.x];
}

// ------------- reduce partials -> updates(bf16) = U / (rowsum + eps) -------------
__global__ __launch_bounds__(256) void attn_reduce(
        const float* __restrict__ Up, const float* __restrict__ rsp,
        unsigned short* __restrict__ upd) {
    const int bs = blockIdx.x;  // grid 384 (pad rows -> zeros)
    if (bs >= 352) {
        for (int d = threadIdx.x; d < 512; d += 256) upd[(size_t)bs * 512 + d] = 0;
        return;
    }
    const int b = bs / 11, s = bs - b * 11;
    float rsum = ATTN_EPS;
    #pragma unroll
    for (int c = 0; c < NCHUNK; ++c) rsum += rsp[((size_t)b * NCHUNK + c) * 11 + s];
    const float inv = 1.0f / rsum;
    for (int d = threadIdx.x; d < 512; d += 256) {
        float acc = 0.f;
        #pragma unroll
        for (int c = 0; c < NCHUNK; ++c) acc += Up[(((size_t)b * NCHUNK + c) * 11 + s) * 512 + d];
        upd[(size_t)bs * 512 + d] = f2bf(acc * inv);
    }
}

// ---------------- fused GRU + MLP-LayerNorm: gi,gh,slots -> mln(bf16) ----------------
__global__ __launch_bounds__(256) void gru_ln(
        const float* __restrict__ gi, const float* __restrict__ gh,
        const float* __restrict__ slots, const float* __restrict__ g,
        const float* __restrict__ b, unsigned short* __restrict__ mln) {
    int row = blockIdx.x * 4 + (threadIdx.x >> 6);
    int lane = threadIdx.x & 63;
    unsigned short* orow = mln + (size_t)row * 512;
    if (row >= 352) {  // pad rows: finite zeros
        ushort4v z; z.x = z.y = z.z = z.w = 0;
        *(ushort4v*)(orow + lane * 4) = z;
        *(ushort4v*)(orow + 256 + lane * 4) = z;
        return;
    }
    const float4* gir = (const float4*)(gi + (size_t)row * 1536);
    const float4* ghr = (const float4*)(gh + (size_t)row * 1536);
    const float4* sr  = (const float4*)(slots + (size_t)row * 512);
    float v[8];
    #pragma unroll
    for (int half = 0; half < 2; ++half) {
        int o = half * 64 + lane;
        float4 ir = gir[o], iz = gir[128 + o], in_ = gir[256 + o];
        float4 hr = ghr[o], hz = ghr[128 + o], hn = ghr[256 + o];
        float4 sv = sr[o];
        float rr[4], zz[4], nn[4];
        rr[0] = 1.f / (1.f + __expf(-(ir.x + hr.x)));
        rr[1] = 1.f / (1.f + __expf(-(ir.y + hr.y)));
        rr[2] = 1.f / (1.f + __expf(-(ir.z + hr.z)));
        rr[3] = 1.f / (1.f + __expf(-(ir.w + hr.w)));
        zz[0] = 1.f / (1.f + __expf(-(iz.x + hz.x)));
        zz[1] = 1.f / (1.f + __expf(-(iz.y + hz.y)));
        zz[2] = 1.f / (1.f + __expf(-(iz.z + hz.z)));
        zz[3] = 1.f / (1.f + __expf(-(iz.w + hz.w)));
        nn[0] = tanhf(in_.x + rr[0] * hn.x);
        nn[1] = tanhf(in_.y + rr[1] * hn.y);
        nn[2] = tanhf(in_.z + rr[2] * hn.z);
        nn[3] = tanhf(in_.w + rr[3] * hn.w);
        v[half * 4 + 0] = (1.f - zz[0]) * nn[0] + zz[0] * sv.x;
        v[half * 4 + 1] = (1.f - zz[1]) * nn[1] + zz[1] * sv.y;
        v[half * 4 + 2] = (1.f - zz[2]) * nn[2] + zz[2] * sv.z;
        v[half * 4 + 3] = (1.f - zz[3]) * nn[3] + zz[3] * sv.w;
    }
    float s = 0.f, ss = 0.f;
    #pragma unroll
    for (int j = 0; j < 8; ++j) { s += v[j]; ss += v[j] * v[j]; }
    #pragma unroll
    for (int off = 32; off > 0; off >>= 1) {
        s  += __shfl_xor(s, off, 64);
        ss += __shfl_xor(ss, off, 64);
    }
    float mu = s * (1.0f / 512.0f);
    float var = ss * (1.0f / 512.0f) - mu * mu;
    float rstd = rsqrtf(var + LN_EPS);
    float4 g0 = ((const float4*)g)[lane], g1 = ((const float4*)g)[lane + 64];
    float4 b0 = ((const float4*)b)[lane], b1 = ((const float4*)b)[lane + 64];
    ushort4v o0, o1;
    o0.x = f2bf((v[0] - mu) * rstd * g0.x + b0.x);
    o0.y = f2bf((v[1] - mu) * rstd * g0.y + b0.y);
    o0.z = f2bf((v[2] - mu) * rstd * g0.z + b0.z);
    o0.w = f2bf((v[3] - mu) * rstd * g0.w + b0.w);
    o1.x = f2bf((v[4] - mu) * rstd * g1.x + b1.x);
    o1.y = f2bf((v[5] - mu) * rstd * g1.y + b1.y);
    o1.z = f2bf((v[6] - mu) * rstd * g1.z + b1.z);
    o1.w = f2bf((v[7] - mu) * rstd * g1.w + b1.w);
    *(ushort4v*)(orow + lane * 4) = o0;
    *(ushort4v*)(orow + 256 + lane * 4) = o1;
}

extern "C" void kernel_launch(void* const* d_in, const int* in_sizes, int n_in,
                              void* d_out, int out_size, void* d_ws, size_t ws_size,
                              hipStream_t stream) {
    const float* slots_in = (const float*)d_in[0];
    const float* inputs   = (const float*)d_in[1];
    const float* ln_in_g  = (const float*)d_in[2];
    const float* ln_in_b  = (const float*)d_in[3];
    const float* Wk  = (const float*)d_in[4];
    const float* bk  = (const float*)d_in[5];
    const float* Wv  = (const float*)d_in[6];
    const float* bv  = (const float*)d_in[7];
    const float* ln_q_g = (const float*)d_in[8];
    const float* ln_q_b = (const float*)d_in[9];
    const float* Wq  = (const float*)d_in[10];
    const float* W_ih = (const float*)d_in[11];
    const float* b_ih = (const float*)d_in[12];
    const float* W_hh = (const float*)d_in[13];
    const float* b_hh = (const float*)d_in[14];
    const float* ln_m_g = (const float*)d_in[15];
    const float* ln_m_b = (const float*)d_in[16];
    const float* W1 = (const float*)d_in[17];
    const float* b1 = (const float*)d_in[18];
    const float* W2 = (const float*)d_in[19];
    const float* b2 = (const float*)d_in[20];

    char* p = (char*)d_ws;
    auto alloc = [&](size_t bytes) { char* r = p; p += (bytes + 255) & ~(size_t)255; return r; };
    unsigned short* xln = (unsigned short*)alloc(131072ull * 512 * 2);
    unsigned short* wt  = (unsigned short*)alloc(1024ull * 512 * 2);
    unsigned short* kbf = (unsigned short*)alloc(32ull * 4096 * 512 * 2);
    unsigned short* vbf = (unsigned short*)alloc(32ull * 4096 * 512 * 2);
    unsigned short* WqT   = (unsigned short*)alloc(512ull * 512 * 2);
    unsigned short* Wih_b = (unsigned short*)alloc(1536ull * 512 * 2);
    unsigned short* Whh_b = (unsigned short*)alloc(1536ull * 512 * 2);
    unsigned short* W1T   = (unsigned short*)alloc(2048ull * 512 * 2);
    unsigned short* W2T   = (unsigned short*)alloc(512ull * 2048 * 2);
    unsigned short* slq  = (unsigned short*)alloc(384ull * 512 * 2);
    unsigned short* mln  = (unsigned short*)alloc(384ull * 512 * 2);
    unsigned short* upd  = (unsigned short*)alloc(384ull * 512 * 2);
    unsigned short* slbf = (unsigned short*)alloc(384ull * 512 * 2);
    unsigned short* h1   = (unsigned short*)alloc(384ull * 2048 * 2);
    float* q_    = (float*)alloc(384ull * 512 * 4);
    float* slots = (float*)alloc(384ull * 512 * 4);
    float* gi    = (float*)alloc(384ull * 1536 * 4);
    float* gh    = (float*)alloc(384ull * 1536 * 4);
    float* Up    = (float*)alloc((size_t)32 * NCHUNK * 11 * 512 * 4);
    float* rsp   = (float*)alloc((size_t)32 * NCHUNK * 11 * 4);

    // ---- one-time prep ----
    ln512_kernel<true><<<dim3(32768), 256, 0, stream>>>(inputs, ln_in_g, ln_in_b, xln, 131072, 131072, 1.0f);
    prep_wt<<<dim3(2048), 256, 0, stream>>>(Wk, Wv, wt);
    transpose_bf<<<dim3(16, 16), 256, 0, stream>>>(Wq, WqT, 512, 512);
    conv_bf<<<dim3(3072), 256, 0, stream>>>(W_ih, Wih_b, 1536 * 512);
    conv_bf<<<dim3(3072), 256, 0, stream>>>(W_hh, Whh_b, 1536 * 512);
    transpose_bf<<<dim3(64, 16), 256, 0, stream>>>(W1, W1T, 512, 2048);
    transpose_bf<<<dim3(16, 64), 256, 0, stream>>>(W2, W2T, 2048, 512);
    kv_gemm<<<dim3(8192), 256, 0, stream>>>(xln, wt, bk, bv, kbf, vbf);
    hipMemcpyAsync(slots, slots_in, 352ull * 512 * 4, hipMemcpyDeviceToDevice, stream);
    conv_bf_rows<<<dim3(768), 256, 0, stream>>>(slots_in, slbf, 384, 352);

    const float qscale = 0.044194173824159216f;  // 1/sqrt(512)
    for (int it = 0; it < 3; ++it) {
        ln512_kernel<true><<<dim3(96), 256, 0, stream>>>(slots, ln_q_g, ln_q_b, slq, 384, 352, qscale);
        rgemm<false, false, 0><<<dim3(8, 6), 64, 0, stream>>>(slq, WqT, nullptr, q_, nullptr, 512, 512);
        attn_kernel<<<dim3(NCHUNK, 32), 256, 0, stream>>>(q_, kbf, vbf, Up, rsp);
        attn_reduce<<<dim3(384), 256, 0, stream>>>(Up, rsp, upd);
        gru_gemm<<<dim3(24, 6, 2), 64, 0, stream>>>(upd, slbf, Wih_b, Whh_b, b_ih, b_hh, gi, gh);
        gru_ln<<<dim3(96), 256, 0, stream>>>(gi, gh, slots, ln_m_g, ln_m_b, mln);
        rgemm<true, true, 1><<<dim3(32, 6), 64, 0, stream>>>(mln, W1T, b1, nullptr, h1, 2048, 512);
        rgemm<true, false, 2><<<dim3(8, 6), 64, 0, stream>>>(h1, W2T, b2, slots, slbf, 512, 2048);
    }
    hipMemcpyAsync(d_out, slots, (size_t)out_size * 4, hipMemcpyDeviceToDevice, stream);
}

// Round 5
// 1214.666 us; speedup vs baseline: 1.2072x; 1.2072x over previous
//
#include <hip/hip_runtime.h>
#include <cstdint>
#include <cstddef>

typedef short bf16x8 __attribute__((ext_vector_type(8)));
typedef float floatx4 __attribute__((ext_vector_type(4)));
typedef unsigned short ushort4v __attribute__((ext_vector_type(4)));

#define LN_EPS 1e-5f
#define ATTN_EPS 1e-8f
#define NCHUNK 32

__device__ __forceinline__ unsigned short f2bf(float f) {
    unsigned int u = __float_as_uint(f);
    u += 0x7fffu + ((u >> 16) & 1u);
    return (unsigned short)(u >> 16);
}

__device__ __forceinline__ void load_lds16(const void* gp, void* lp) {
    __builtin_amdgcn_global_load_lds(
        (__attribute__((address_space(1))) void*)gp,
        (__attribute__((address_space(3))) void*)lp,
        16, 0, 0);
}

// ---------------- LayerNorm over rows of 512, one wave per row ----------------
template<bool OUT_BF16>
__global__ __launch_bounds__(256) void ln512_kernel(
        const float* __restrict__ x, const float* __restrict__ g, const float* __restrict__ b,
        void* __restrict__ out, int total_rows, int data_rows, float outscale) {
    int row = blockIdx.x * 4 + (threadIdx.x >> 6);
    int lane = threadIdx.x & 63;
    if (row >= total_rows) return;
    int rr = row < data_rows ? row : data_rows - 1;
    const float4* xr = (const float4*)(x + (size_t)rr * 512);
    float4 a0 = xr[lane];
    float4 a1 = xr[lane + 64];
    float s  = a0.x + a0.y + a0.z + a0.w + a1.x + a1.y + a1.z + a1.w;
    float ss = a0.x*a0.x + a0.y*a0.y + a0.z*a0.z + a0.w*a0.w
             + a1.x*a1.x + a1.y*a1.y + a1.z*a1.z + a1.w*a1.w;
    #pragma unroll
    for (int off = 32; off > 0; off >>= 1) {
        s  += __shfl_xor(s, off, 64);
        ss += __shfl_xor(ss, off, 64);
    }
    float mu = s * (1.0f / 512.0f);
    float var = ss * (1.0f / 512.0f) - mu * mu;
    float rstd = rsqrtf(var + LN_EPS);
    float4 g0 = ((const float4*)g)[lane];
    float4 g1 = ((const float4*)g)[lane + 64];
    float4 b0 = ((const float4*)b)[lane];
    float4 b1 = ((const float4*)b)[lane + 64];
    float y[8];
    y[0] = ((a0.x - mu) * rstd * g0.x + b0.x) * outscale;
    y[1] = ((a0.y - mu) * rstd * g0.y + b0.y) * outscale;
    y[2] = ((a0.z - mu) * rstd * g0.z + b0.z) * outscale;
    y[3] = ((a0.w - mu) * rstd * g0.w + b0.w) * outscale;
    y[4] = ((a1.x - mu) * rstd * g1.x + b1.x) * outscale;
    y[5] = ((a1.y - mu) * rstd * g1.y + b1.y) * outscale;
    y[6] = ((a1.z - mu) * rstd * g1.z + b1.z) * outscale;
    y[7] = ((a1.w - mu) * rstd * g1.w + b1.w) * outscale;
    if (OUT_BF16) {
        unsigned short* orow = (unsigned short*)out + (size_t)row * 512;
        ushort4v o0, o1;
        o0.x = f2bf(y[0]); o0.y = f2bf(y[1]); o0.z = f2bf(y[2]); o0.w = f2bf(y[3]);
        o1.x = f2bf(y[4]); o1.y = f2bf(y[5]); o1.z = f2bf(y[6]); o1.w = f2bf(y[7]);
        *(ushort4v*)(orow + lane * 4) = o0;
        *(ushort4v*)(orow + 256 + lane * 4) = o1;
    } else {
        float* orow = (float*)out + (size_t)row * 512;
        *(float4*)(orow + lane * 4) = make_float4(y[0], y[1], y[2], y[3]);
        *(float4*)(orow + 256 + lane * 4) = make_float4(y[4], y[5], y[6], y[7]);
    }
}

// ---------------- fused one-time prep: all weight transposes/converts + slbf ----------------
__device__ __forceinline__ void tr32(const float* __restrict__ in, unsigned short* __restrict__ out,
                                     int R, int C, int bx, int by, float (*tile)[33]) {
    int tx = threadIdx.x & 31, ty = threadIdx.x >> 5;
    #pragma unroll
    for (int i = 0; i < 32; i += 8)
        tile[ty + i][tx] = in[(size_t)(by + ty + i) * C + bx + tx];
    __syncthreads();
    #pragma unroll
    for (int i = 0; i < 32; i += 8)
        out[(size_t)(bx + ty + i) * R + by + tx] = f2bf(tile[tx][ty + i]);
}

__global__ __launch_bounds__(256) void prep_all(
        const float* __restrict__ Wk, const float* __restrict__ Wv,
        const float* __restrict__ Wq, const float* __restrict__ W1,
        const float* __restrict__ W2, const float* __restrict__ W_ih,
        const float* __restrict__ W_hh, const float* __restrict__ slots_in,
        unsigned short* __restrict__ wt, unsigned short* __restrict__ WqT,
        unsigned short* __restrict__ W1T, unsigned short* __restrict__ W2T,
        unsigned short* __restrict__ Wih_b, unsigned short* __restrict__ Whh_b,
        unsigned short* __restrict__ slbf) {
    __shared__ float tile[32][33];
    const int b = blockIdx.x;
    const int t = threadIdx.x;
    if (b < 256) {                       // Wk^T -> wt[0:512]
        int i = b;
        tr32(Wk, wt, 512, 512, (i & 15) * 32, (i >> 4) * 32, tile);
    } else if (b < 512) {                // Wv^T -> wt[512:1024]
        int i = b - 256;
        tr32(Wv, wt + 512 * 512, 512, 512, (i & 15) * 32, (i >> 4) * 32, tile);
    } else if (b < 768) {                // Wq^T
        int i = b - 512;
        tr32(Wq, WqT, 512, 512, (i & 15) * 32, (i >> 4) * 32, tile);
    } else if (b < 1792) {               // W1 [512][2048] -> W1T [2048][512]
        int i = b - 768;
        tr32(W1, W1T, 512, 2048, (i & 63) * 32, (i >> 6) * 32, tile);
    } else if (b < 2816) {               // W2 [2048][512] -> W2T [512][2048]
        int i = b - 1792;
        tr32(W2, W2T, 2048, 512, (i & 15) * 32, (i >> 4) * 32, tile);
    } else if (b < 5888) {               // Wih convert (row-major keep)
        int idx = (b - 2816) * 256 + t;
        Wih_b[idx] = f2bf(W_ih[idx]);
    } else if (b < 8960) {               // Whh convert
        int idx = (b - 5888) * 256 + t;
        Whh_b[idx] = f2bf(W_hh[idx]);
    } else {                             // slbf: bf16 slots, 384-row padded
        int idx = (b - 8960) * 256 + t;  // over 384*512
        int row = idx >> 9, d = idx & 511;
        int rr = row < 352 ? row : 351;
        slbf[idx] = f2bf(slots_in[(size_t)rr * 512 + d]);
    }
}

// ---------------- k/v projection GEMM: [131072x512] @ [512x1024] ----------------
// 256x128 tile, 8 waves (4x2 of 64x64), BK=64, XOR-swizzled LDS, XCD-stripe grid.
__global__ __launch_bounds__(512) void kv_gemm(
        const unsigned short* __restrict__ xln, const unsigned short* __restrict__ wt,
        const float* __restrict__ bk, const float* __restrict__ bv,
        unsigned short* __restrict__ kout, unsigned short* __restrict__ vout) {
    __shared__ unsigned short As[256 * 64];   // 32 KB
    __shared__ unsigned short Bs[128 * 64];   // 16 KB
    const int t = threadIdx.x;
    const int lane = t & 63;
    const int w = t >> 6;                 // 0..7
    const int wm = w >> 1, wn = w & 1;    // 4 x 2
    const int id = blockIdx.x;
    const int xcd = id & 7;
    const int slot = id >> 3;
    const int n0 = (slot & 7) * 128;
    const int m0 = (((slot >> 3) << 3) | xcd) * 256;
    const int quad = lane >> 4;
    const int l15 = lane & 15;
    floatx4 acc[4][4];
    #pragma unroll
    for (int i = 0; i < 4; ++i)
        #pragma unroll
        for (int j = 0; j < 4; ++j)
            #pragma unroll
            for (int r = 0; r < 4; ++r) acc[i][j][r] = 0.0f;

    for (int k0 = 0; k0 < 512; k0 += 64) {
        #pragma unroll
        for (int p = 0; p < 4; ++p) {       // A: 2048 chunks of 16B
            const int s = p * 512 + t;
            const int row = s >> 3;
            const int c = (s & 7) ^ (row & 7);
            const int ldsoff = (s - lane) * 16;
            load_lds16(xln + (size_t)(m0 + row) * 512 + k0 + c * 8, (char*)As + ldsoff);
        }
        #pragma unroll
        for (int p = 0; p < 2; ++p) {       // B: 1024 chunks
            const int s = p * 512 + t;
            const int row = s >> 3;
            const int c = (s & 7) ^ (row & 7);
            const int ldsoff = (s - lane) * 16;
            load_lds16(wt + (size_t)(n0 + row) * 512 + k0 + c * 8, (char*)Bs + ldsoff);
        }
        __builtin_amdgcn_s_waitcnt(0);
        __syncthreads();
        #pragma unroll
        for (int h = 0; h < 2; ++h) {
            bf16x8 af[4], bfr[4];
            #pragma unroll
            for (int i = 0; i < 4; ++i) {
                const int row = wm * 64 + i * 16 + l15;
                const int cp = ((h << 2) | quad) ^ (l15 & 7);
                af[i] = *(const bf16x8*)(As + row * 64 + cp * 8);
            }
            #pragma unroll
            for (int j = 0; j < 4; ++j) {
                const int row = wn * 64 + j * 16 + l15;
                const int cp = ((h << 2) | quad) ^ (l15 & 7);
                bfr[j] = *(const bf16x8*)(Bs + row * 64 + cp * 8);
            }
            #pragma unroll
            for (int i = 0; i < 4; ++i)
                #pragma unroll
                for (int j = 0; j < 4; ++j)
                    acc[i][j] = __builtin_amdgcn_mfma_f32_16x16x32_bf16(af[i], bfr[j], acc[i][j], 0, 0, 0);
        }
        __syncthreads();
    }
    #pragma unroll
    for (int j = 0; j < 4; ++j) {
        const int n = n0 + wn * 64 + j * 16 + l15;
        const bool isk = (n < 512);
        const float bias = isk ? bk[n] : bv[n - 512];
        unsigned short* outp = isk ? kout : vout;
        const int nc = isk ? n : n - 512;
        #pragma unroll
        for (int i = 0; i < 4; ++i) {
            #pragma unroll
            for (int r = 0; r < 4; ++r) {
                const int m = m0 + wm * 64 + i * 16 + quad * 4 + r;
                outp[(size_t)m * 512 + nc] = f2bf(acc[i][j][r] + bias);
            }
        }
    }
}

// ---------------- small bf16 MFMA GEMM core: 64x64 tile, BK=64, swizzled LDS ----------------
// OUT_MODE: 0 = fp32 Cf, 1 = bf16 Cb, 2 = both.
template<bool BIAS, bool RELU, int OUT_MODE>
__device__ __forceinline__ void hgemm_core(
        const unsigned short* __restrict__ A, const unsigned short* __restrict__ Bt,
        const float* __restrict__ bias, float* __restrict__ Cf,
        unsigned short* __restrict__ Cb, int m0, int n0, int N, int K,
        unsigned short* As, unsigned short* Bs) {
    const int t = threadIdx.x;
    const int lane = t & 63;
    const int w = t >> 6;
    const int wm = w >> 1, wn = w & 1;
    const int quad = lane >> 4;
    const int l15 = lane & 15;
    floatx4 acc[2][2];
    #pragma unroll
    for (int i = 0; i < 2; ++i)
        #pragma unroll
        for (int j = 0; j < 2; ++j)
            #pragma unroll
            for (int r = 0; r < 4; ++r) acc[i][j][r] = 0.0f;

    for (int k0 = 0; k0 < K; k0 += 64) {
        #pragma unroll
        for (int p = 0; p < 2; ++p) {
            const int s = p * 256 + t;
            const int row = s >> 3;
            const int c = (s & 7) ^ (row & 7);
            const int ldsoff = (s - lane) * 16;
            load_lds16(A  + (size_t)(m0 + row) * K + k0 + c * 8, (char*)As + ldsoff);
            load_lds16(Bt + (size_t)(n0 + row) * K + k0 + c * 8, (char*)Bs + ldsoff);
        }
        __builtin_amdgcn_s_waitcnt(0);
        __syncthreads();
        #pragma unroll
        for (int h = 0; h < 2; ++h) {
            bf16x8 af[2], bfr[2];
            #pragma unroll
            for (int i = 0; i < 2; ++i) {
                const int row = wm * 32 + i * 16 + l15;
                const int cp = ((h << 2) | quad) ^ (l15 & 7);
                af[i] = *(const bf16x8*)(As + row * 64 + cp * 8);
            }
            #pragma unroll
            for (int j = 0; j < 2; ++j) {
                const int row = wn * 32 + j * 16 + l15;
                const int cp = ((h << 2) | quad) ^ (l15 & 7);
                bfr[j] = *(const bf16x8*)(Bs + row * 64 + cp * 8);
            }
            #pragma unroll
            for (int i = 0; i < 2; ++i)
                #pragma unroll
                for (int j = 0; j < 2; ++j)
                    acc[i][j] = __builtin_amdgcn_mfma_f32_16x16x32_bf16(af[i], bfr[j], acc[i][j], 0, 0, 0);
        }
        __syncthreads();
    }
    #pragma unroll
    for (int j = 0; j < 2; ++j) {
        const int n = n0 + wn * 32 + j * 16 + l15;
        const float bb = BIAS ? bias[n] : 0.0f;
        #pragma unroll
        for (int i = 0; i < 2; ++i) {
            #pragma unroll
            for (int r = 0; r < 4; ++r) {
                const int m = m0 + wm * 32 + i * 16 + quad * 4 + r;
                float v = acc[i][j][r] + bb;
                if (RELU) v = fmaxf(v, 0.0f);
                if (OUT_MODE == 0 || OUT_MODE == 2) Cf[(size_t)m * N + n] = v;
                if (OUT_MODE == 1 || OUT_MODE == 2) Cb[(size_t)m * N + n] = f2bf(v);
            }
        }
    }
}

template<bool BIAS, bool RELU, int OUT_MODE>
__global__ __launch_bounds__(256) void hgemm(
        const unsigned short* __restrict__ A, const unsigned short* __restrict__ Bt,
        const float* __restrict__ bias, float* __restrict__ Cf,
        unsigned short* __restrict__ Cb, int N, int K) {
    __shared__ unsigned short As[64 * 64];
    __shared__ unsigned short Bs[64 * 64];
    hgemm_core<BIAS, RELU, OUT_MODE>(A, Bt, bias, Cf, Cb,
                                     blockIdx.y * 64, blockIdx.x * 64, N, K, As, Bs);
}

// gi and gh in one launch (blockIdx.z selects)
__global__ __launch_bounds__(256) void gru_gemm(
        const unsigned short* __restrict__ upd, const unsigned short* __restrict__ slbf,
        const unsigned short* __restrict__ Wih, const unsigned short* __restrict__ Whh,
        const float* __restrict__ bih, const float* __restrict__ bhh,
        float* __restrict__ gi, float* __restrict__ gh) {
    __shared__ unsigned short As[64 * 64];
    __shared__ unsigned short Bs[64 * 64];
    if (blockIdx.z == 0)
        hgemm_core<true, false, 0>(upd, Wih, bih, gi, nullptr,
                                   blockIdx.y * 64, blockIdx.x * 64, 1536, 512, As, Bs);
    else
        hgemm_core<true, false, 0>(slbf, Whh, bhh, gh, nullptr,
                                   blockIdx.y * 64, blockIdx.x * 64, 1536, 512, As, Bs);
}

// ---------------- fused inverted attention ----------------
__global__ __launch_bounds__(256) void attn_kernel(
        const float* __restrict__ q, const unsigned short* __restrict__ kbf,
        const unsigned short* __restrict__ vbf,
        float* __restrict__ Up, float* __restrict__ rsp) {
    const int b = blockIdx.y;
    const int chunk = blockIdx.x;
    const int w = threadIdx.x >> 6, lane = threadIdx.x & 63;
    const int d0 = lane * 8;
    const int NPC = 4096 / NCHUNK;

    float qr[11][8];
    {
        const float* qb = q + (size_t)b * 11 * 512 + d0;
        #pragma unroll
        for (int s = 0; s < 11; ++s) {
            float4 q0 = *(const float4*)(qb + s * 512);
            float4 q1 = *(const float4*)(qb + s * 512 + 4);
            qr[s][0] = q0.x; qr[s][1] = q0.y; qr[s][2] = q0.z; qr[s][3] = q0.w;
            qr[s][4] = q1.x; qr[s][5] = q1.y; qr[s][6] = q1.z; qr[s][7] = q1.w;
        }
    }
    float U[11][8];
    float rs[11];
    #pragma unroll
    for (int s = 0; s < 11; ++s) {
        rs[s] = 0.f;
        #pragma unroll
        for (int j = 0; j < 8; ++j) U[s][j] = 0.f;
    }

    const size_t base = ((size_t)b * 4096 + (size_t)chunk * NPC) * 512 + d0;
    for (int nn = w; nn < NPC; nn += 4) {
        const unsigned short* kp = kbf + base + (size_t)nn * 512;
        const unsigned short* vp = vbf + base + (size_t)nn * 512;
        uint4 kr = *(const uint4*)kp;
        float kf[8];
        kf[0] = __uint_as_float(kr.x << 16); kf[1] = __uint_as_float(kr.x & 0xffff0000u);
        kf[2] = __uint_as_float(kr.y << 16); kf[3] = __uint_as_float(kr.y & 0xffff0000u);
        kf[4] = __uint_as_float(kr.z << 16); kf[5] = __uint_as_float(kr.z & 0xffff0000u);
        kf[6] = __uint_as_float(kr.w << 16); kf[7] = __uint_as_float(kr.w & 0xffff0000u);
        float l[11];
        #pragma unroll
        for (int s = 0; s < 11; ++s) {
            float p = kf[0] * qr[s][0];
            #pragma unroll
            for (int j = 1; j < 8; ++j) p = fmaf(kf[j], qr[s][j], p);
            l[s] = p;
        }
        #pragma unroll
        for (int off = 32; off > 0; off >>= 1)
            #pragma unroll
            for (int s = 0; s < 11; ++s) l[s] += __shfl_xor(l[s], off, 64);
        float mx = l[0];
        #pragma unroll
        for (int s = 1; s < 11; ++s) mx = fmaxf(mx, l[s]);
        float se = 0.f;
        #pragma unroll
        for (int s = 0; s < 11; ++s) { l[s] = __expf(l[s] - mx); se += l[s]; }
        float inv = 1.0f / se;
        uint4 vr = *(const uint4*)vp;
        float vf[8];
        vf[0] = __uint_as_float(vr.x << 16); vf[1] = __uint_as_float(vr.x & 0xffff0000u);
        vf[2] = __uint_as_float(vr.y << 16); vf[3] = __uint_as_float(vr.y & 0xffff0000u);
        vf[4] = __uint_as_float(vr.z << 16); vf[5] = __uint_as_float(vr.z & 0xffff0000u);
        vf[6] = __uint_as_float(vr.w << 16); vf[7] = __uint_as_float(vr.w & 0xffff0000u);
        #pragma unroll
        for (int s = 0; s < 11; ++s) {
            float a = l[s] * inv;
            rs[s] += a;
            #pragma unroll
            for (int j = 0; j < 8; ++j) U[s][j] = fmaf(a, vf[j], U[s][j]);
        }
    }
    __shared__ float Us[11 * 512];
    __shared__ float rss[11];
    for (int ph = 0; ph < 4; ++ph) {
        if (w == ph) {
            #pragma unroll
            for (int s = 0; s < 11; ++s) {
                #pragma unroll
                for (int j = 0; j < 8; ++j) {
                    if (ph == 0) Us[s * 512 + d0 + j] = U[s][j];
                    else         Us[s * 512 + d0 + j] += U[s][j];
                }
            }
            if (lane == 0) {
                #pragma unroll
                for (int s = 0; s < 11; ++s) {
                    if (ph == 0) rss[s] = rs[s]; else rss[s] += rs[s];
                }
            }
        }
        __syncthreads();
    }
    float* up = Up + ((size_t)b * NCHUNK + chunk) * 11 * 512;
    for (int idx = threadIdx.x; idx < 11 * 512; idx += 256) up[idx] = Us[idx];
    if (threadIdx.x < 11) rsp[((size_t)b * NCHUNK + chunk) * 11 + threadIdx.x] = rss[threadIdx.x];
}

// ------------- reduce partials -> updates(bf16) = U / (rowsum + eps) -------------
__global__ __launch_bounds__(256) void attn_reduce(
        const float* __restrict__ Up, const float* __restrict__ rsp,
        unsigned short* __restrict__ upd) {
    const int bs = blockIdx.x;  // grid 384 (pad rows -> zeros)
    if (bs >= 352) {
        for (int d = threadIdx.x; d < 512; d += 256) upd[(size_t)bs * 512 + d] = 0;
        return;
    }
    const int b = bs / 11, s = bs - b * 11;
    float rsum = ATTN_EPS;
    #pragma unroll
    for (int c = 0; c < NCHUNK; ++c) rsum += rsp[((size_t)b * NCHUNK + c) * 11 + s];
    const float inv = 1.0f / rsum;
    for (int d = threadIdx.x; d < 512; d += 256) {
        float acc = 0.f;
        #pragma unroll
        for (int c = 0; c < NCHUNK; ++c) acc += Up[(((size_t)b * NCHUNK + c) * 11 + s) * 512 + d];
        upd[(size_t)bs * 512 + d] = f2bf(acc * inv);
    }
}

// ---------------- fused GRU + MLP-LayerNorm: gi,gh,slots -> mln(bf16) ----------------
__global__ __launch_bounds__(256) void gru_ln(
        const float* __restrict__ gi, const float* __restrict__ gh,
        const float* __restrict__ slots, const float* __restrict__ g,
        const float* __restrict__ b, unsigned short* __restrict__ mln) {
    int row = blockIdx.x * 4 + (threadIdx.x >> 6);
    int lane = threadIdx.x & 63;
    unsigned short* orow = mln + (size_t)row * 512;
    if (row >= 352) {  // pad rows: finite zeros
        ushort4v z; z.x = z.y = z.z = z.w = 0;
        *(ushort4v*)(orow + lane * 4) = z;
        *(ushort4v*)(orow + 256 + lane * 4) = z;
        return;
    }
    const float4* gir = (const float4*)(gi + (size_t)row * 1536);
    const float4* ghr = (const float4*)(gh + (size_t)row * 1536);
    const float4* sr  = (const float4*)(slots + (size_t)row * 512);
    float v[8];
    #pragma unroll
    for (int half = 0; half < 2; ++half) {
        int o = half * 64 + lane;
        float4 ir = gir[o], iz = gir[128 + o], in_ = gir[256 + o];
        float4 hr = ghr[o], hz = ghr[128 + o], hn = ghr[256 + o];
        float4 sv = sr[o];
        float rr[4], zz[4], nn[4];
        rr[0] = 1.f / (1.f + __expf(-(ir.x + hr.x)));
        rr[1] = 1.f / (1.f + __expf(-(ir.y + hr.y)));
        rr[2] = 1.f / (1.f + __expf(-(ir.z + hr.z)));
        rr[3] = 1.f / (1.f + __expf(-(ir.w + hr.w)));
        zz[0] = 1.f / (1.f + __expf(-(iz.x + hz.x)));
        zz[1] = 1.f / (1.f + __expf(-(iz.y + hz.y)));
        zz[2] = 1.f / (1.f + __expf(-(iz.z + hz.z)));
        zz[3] = 1.f / (1.f + __expf(-(iz.w + hz.w)));
        nn[0] = tanhf(in_.x + rr[0] * hn.x);
        nn[1] = tanhf(in_.y + rr[1] * hn.y);
        nn[2] = tanhf(in_.z + rr[2] * hn.z);
        nn[3] = tanhf(in_.w + rr[3] * hn.w);
        v[half * 4 + 0] = (1.f - zz[0]) * nn[0] + zz[0] * sv.x;
        v[half * 4 + 1] = (1.f - zz[1]) * nn[1] + zz[1] * sv.y;
        v[half * 4 + 2] = (1.f - zz[2]) * nn[2] + zz[2] * sv.z;
        v[half * 4 + 3] = (1.f - zz[3]) * nn[3] + zz[3] * sv.w;
    }
    float s = 0.f, ss = 0.f;
    #pragma unroll
    for (int j = 0; j < 8; ++j) { s += v[j]; ss += v[j] * v[j]; }
    #pragma unroll
    for (int off = 32; off > 0; off >>= 1) {
        s  += __shfl_xor(s, off, 64);
        ss += __shfl_xor(ss, off, 64);
    }
    float mu = s * (1.0f / 512.0f);
    float var = ss * (1.0f / 512.0f) - mu * mu;
    float rstd = rsqrtf(var + LN_EPS);
    float4 g0 = ((const float4*)g)[lane], g1 = ((const float4*)g)[lane + 64];
    float4 b0 = ((const float4*)b)[lane], b1 = ((const float4*)b)[lane + 64];
    ushort4v o0, o1;
    o0.x = f2bf((v[0] - mu) * rstd * g0.x + b0.x);
    o0.y = f2bf((v[1] - mu) * rstd * g0.y + b0.y);
    o0.z = f2bf((v[2] - mu) * rstd * g0.z + b0.z);
    o0.w = f2bf((v[3] - mu) * rstd * g0.w + b0.w);
    o1.x = f2bf((v[4] - mu) * rstd * g1.x + b1.x);
    o1.y = f2bf((v[5] - mu) * rstd * g1.y + b1.y);
    o1.z = f2bf((v[6] - mu) * rstd * g1.z + b1.z);
    o1.w = f2bf((v[7] - mu) * rstd * g1.w + b1.w);
    *(ushort4v*)(orow + lane * 4) = o0;
    *(ushort4v*)(orow + 256 + lane * 4) = o1;
}

extern "C" void kernel_launch(void* const* d_in, const int* in_sizes, int n_in,
                              void* d_out, int out_size, void* d_ws, size_t ws_size,
                              hipStream_t stream) {
    const float* slots_in = (const float*)d_in[0];
    const float* inputs   = (const float*)d_in[1];
    const float* ln_in_g  = (const float*)d_in[2];
    const float* ln_in_b  = (const float*)d_in[3];
    const float* Wk  = (const float*)d_in[4];
    const float* bk  = (const float*)d_in[5];
    const float* Wv  = (const float*)d_in[6];
    const float* bv  = (const float*)d_in[7];
    const float* ln_q_g = (const float*)d_in[8];
    const float* ln_q_b = (const float*)d_in[9];
    const float* Wq  = (const float*)d_in[10];
    const float* W_ih = (const float*)d_in[11];
    const float* b_ih = (const float*)d_in[12];
    const float* W_hh = (const float*)d_in[13];
    const float* b_hh = (const float*)d_in[14];
    const float* ln_m_g = (const float*)d_in[15];
    const float* ln_m_b = (const float*)d_in[16];
    const float* W1 = (const float*)d_in[17];
    const float* b1 = (const float*)d_in[18];
    const float* W2 = (const float*)d_in[19];
    const float* b2 = (const float*)d_in[20];

    char* p = (char*)d_ws;
    auto alloc = [&](size_t bytes) { char* r = p; p += (bytes + 255) & ~(size_t)255; return r; };
    unsigned short* xln = (unsigned short*)alloc(131072ull * 512 * 2);
    unsigned short* wt  = (unsigned short*)alloc(1024ull * 512 * 2);
    unsigned short* kbf = (unsigned short*)alloc(32ull * 4096 * 512 * 2);
    unsigned short* vbf = (unsigned short*)alloc(32ull * 4096 * 512 * 2);
    unsigned short* WqT   = (unsigned short*)alloc(512ull * 512 * 2);
    unsigned short* Wih_b = (unsigned short*)alloc(1536ull * 512 * 2);
    unsigned short* Whh_b = (unsigned short*)alloc(1536ull * 512 * 2);
    unsigned short* W1T   = (unsigned short*)alloc(2048ull * 512 * 2);
    unsigned short* W2T   = (unsigned short*)alloc(512ull * 2048 * 2);
    unsigned short* slq  = (unsigned short*)alloc(384ull * 512 * 2);
    unsigned short* mln  = (unsigned short*)alloc(384ull * 512 * 2);
    unsigned short* upd  = (unsigned short*)alloc(384ull * 512 * 2);
    unsigned short* slbf = (unsigned short*)alloc(384ull * 512 * 2);
    unsigned short* h1   = (unsigned short*)alloc(384ull * 2048 * 2);
    float* q_    = (float*)alloc(384ull * 512 * 4);
    float* slots = (float*)alloc(384ull * 512 * 4);
    float* gi    = (float*)alloc(384ull * 1536 * 4);
    float* gh    = (float*)alloc(384ull * 1536 * 4);
    float* Up    = (float*)alloc((size_t)32 * NCHUNK * 11 * 512 * 4);
    float* rsp   = (float*)alloc((size_t)32 * NCHUNK * 11 * 4);

    // ---- one-time prep ----
    ln512_kernel<true><<<dim3(32768), 256, 0, stream>>>(inputs, ln_in_g, ln_in_b, xln, 131072, 131072, 1.0f);
    prep_all<<<dim3(9728), 256, 0, stream>>>(Wk, Wv, Wq, W1, W2, W_ih, W_hh, slots_in,
                                             wt, WqT, W1T, W2T, Wih_b, Whh_b, slbf);
    kv_gemm<<<dim3(4096), 512, 0, stream>>>(xln, wt, bk, bv, kbf, vbf);
    hipMemcpyAsync(slots, slots_in, 352ull * 512 * 4, hipMemcpyDeviceToDevice, stream);

    const float qscale = 0.044194173824159216f;  // 1/sqrt(512)
    for (int it = 0; it < 3; ++it) {
        ln512_kernel<true><<<dim3(96), 256, 0, stream>>>(slots, ln_q_g, ln_q_b, slq, 384, 352, qscale);
        hgemm<false, false, 0><<<dim3(8, 6), 256, 0, stream>>>(slq, WqT, nullptr, q_, nullptr, 512, 512);
        attn_kernel<<<dim3(NCHUNK, 32), 256, 0, stream>>>(q_, kbf, vbf, Up, rsp);
        attn_reduce<<<dim3(384), 256, 0, stream>>>(Up, rsp, upd);
        gru_gemm<<<dim3(24, 6, 2), 256, 0, stream>>>(upd, slbf, Wih_b, Whh_b, b_ih, b_hh, gi, gh);
        gru_ln<<<dim3(96), 256, 0, stream>>>(gi, gh, slots, ln_m_g, ln_m_b, mln);
        hgemm<true, true, 1><<<dim3(32, 6), 256, 0, stream>>>(mln, W1T, b1, nullptr, h1, 2048, 512);
        hgemm<true, false, 2><<<dim3(8, 6), 256, 0, stream>>>(h1, W2T, b2, slots, slbf, 512, 2048);
    }
    hipMemcpyAsync(d_out, slots, (size_t)out_size * 4, hipMemcpyDeviceToDevice, stream);
}

// Round 6
// 958.530 us; speedup vs baseline: 1.5298x; 1.2672x over previous
//
#include <hip/hip_runtime.h>
#include <cstdint>
#include <cstddef>

typedef short bf16x8 __attribute__((ext_vector_type(8)));
typedef float floatx4 __attribute__((ext_vector_type(4)));
typedef unsigned short ushort4v __attribute__((ext_vector_type(4)));

#define LN_EPS 1e-5f
#define ATTN_EPS 1e-8f
#define NCHUNK 32

__device__ __forceinline__ unsigned short f2bf(float f) {
    unsigned int u = __float_as_uint(f);
    u += 0x7fffu + ((u >> 16) & 1u);
    return (unsigned short)(u >> 16);
}

__device__ __forceinline__ void load_lds16(const void* gp, void* lp) {
    __builtin_amdgcn_global_load_lds(
        (__attribute__((address_space(1))) void*)gp,
        (__attribute__((address_space(3))) void*)lp,
        16, 0, 0);
}

// ---------------- LayerNorm over rows of 512, one wave per row ----------------
// QDOT: additionally write cbuf[row] = (LN'd scaled row) . wqbk
template<bool OUT_BF16, bool QDOT>
__global__ __launch_bounds__(256) void ln512_kernel(
        const float* __restrict__ x, const float* __restrict__ g, const float* __restrict__ b,
        void* __restrict__ out, int total_rows, int data_rows, float outscale,
        const float* __restrict__ wqbk, float* __restrict__ cbuf) {
    int row = blockIdx.x * 4 + (threadIdx.x >> 6);
    int lane = threadIdx.x & 63;
    if (row >= total_rows) return;
    int rr = row < data_rows ? row : data_rows - 1;
    const float4* xr = (const float4*)(x + (size_t)rr * 512);
    float4 a0 = xr[lane];
    float4 a1 = xr[lane + 64];
    float s  = a0.x + a0.y + a0.z + a0.w + a1.x + a1.y + a1.z + a1.w;
    float ss = a0.x*a0.x + a0.y*a0.y + a0.z*a0.z + a0.w*a0.w
             + a1.x*a1.x + a1.y*a1.y + a1.z*a1.z + a1.w*a1.w;
    #pragma unroll
    for (int off = 32; off > 0; off >>= 1) {
        s  += __shfl_xor(s, off, 64);
        ss += __shfl_xor(ss, off, 64);
    }
    float mu = s * (1.0f / 512.0f);
    float var = ss * (1.0f / 512.0f) - mu * mu;
    float rstd = rsqrtf(var + LN_EPS);
    float4 g0 = ((const float4*)g)[lane];
    float4 g1 = ((const float4*)g)[lane + 64];
    float4 b0 = ((const float4*)b)[lane];
    float4 b1 = ((const float4*)b)[lane + 64];
    float y[8];
    y[0] = ((a0.x - mu) * rstd * g0.x + b0.x) * outscale;
    y[1] = ((a0.y - mu) * rstd * g0.y + b0.y) * outscale;
    y[2] = ((a0.z - mu) * rstd * g0.z + b0.z) * outscale;
    y[3] = ((a0.w - mu) * rstd * g0.w + b0.w) * outscale;
    y[4] = ((a1.x - mu) * rstd * g1.x + b1.x) * outscale;
    y[5] = ((a1.y - mu) * rstd * g1.y + b1.y) * outscale;
    y[6] = ((a1.z - mu) * rstd * g1.z + b1.z) * outscale;
    y[7] = ((a1.w - mu) * rstd * g1.w + b1.w) * outscale;
    if (QDOT) {
        float4 w0 = ((const float4*)wqbk)[lane];
        float4 w1 = ((const float4*)wqbk)[lane + 64];
        float cd = y[0]*w0.x + y[1]*w0.y + y[2]*w0.z + y[3]*w0.w
                 + y[4]*w1.x + y[5]*w1.y + y[6]*w1.z + y[7]*w1.w;
        #pragma unroll
        for (int off = 32; off > 0; off >>= 1) cd += __shfl_xor(cd, off, 64);
        if (lane == 0) cbuf[row] = cd;
    }
    if (OUT_BF16) {
        unsigned short* orow = (unsigned short*)out + (size_t)row * 512;
        ushort4v o0, o1;
        o0.x = f2bf(y[0]); o0.y = f2bf(y[1]); o0.z = f2bf(y[2]); o0.w = f2bf(y[3]);
        o1.x = f2bf(y[4]); o1.y = f2bf(y[5]); o1.z = f2bf(y[6]); o1.w = f2bf(y[7]);
        *(ushort4v*)(orow + lane * 4) = o0;
        *(ushort4v*)(orow + 256 + lane * 4) = o1;
    } else {
        float* orow = (float*)out + (size_t)row * 512;
        *(float4*)(orow + lane * 4) = make_float4(y[0], y[1], y[2], y[3]);
        *(float4*)(orow + 256 + lane * 4) = make_float4(y[4], y[5], y[6], y[7]);
    }
}

// ---------------- fused one-time prep ----------------
__device__ __forceinline__ void tr32(const float* __restrict__ in, unsigned short* __restrict__ out,
                                     int R, int C, int bx, int by, float (*tile)[33]) {
    int tx = threadIdx.x & 31, ty = threadIdx.x >> 5;
    #pragma unroll
    for (int i = 0; i < 32; i += 8)
        tile[ty + i][tx] = in[(size_t)(by + ty + i) * C + bx + tx];
    __syncthreads();
    #pragma unroll
    for (int i = 0; i < 32; i += 8)
        out[(size_t)(bx + ty + i) * R + by + tx] = f2bf(tile[tx][ty + i]);
}

// row-dot: out[row] = in[row][0..512) . vec   (wave per row)
__device__ __forceinline__ void rowdot512(const float* __restrict__ in, const float* __restrict__ vec,
                                          float* __restrict__ out, int row) {
    int lane = threadIdx.x & 63;
    const float4* r0 = (const float4*)(in + (size_t)row * 512);
    float4 a0 = r0[lane], a1 = r0[lane + 64];
    float4 v0 = ((const float4*)vec)[lane], v1 = ((const float4*)vec)[lane + 64];
    float d = a0.x*v0.x + a0.y*v0.y + a0.z*v0.z + a0.w*v0.w
            + a1.x*v1.x + a1.y*v1.y + a1.z*v1.z + a1.w*v1.w;
    #pragma unroll
    for (int off = 32; off > 0; off >>= 1) d += __shfl_xor(d, off, 64);
    if (lane == 0) out[row] = d;
}

__global__ __launch_bounds__(256) void prep_all(
        const float* __restrict__ Wk, const float* __restrict__ Wq,
        const float* __restrict__ Wv, const float* __restrict__ W_ih,
        const float* __restrict__ W_hh, const float* __restrict__ W1,
        const float* __restrict__ W2, const float* __restrict__ slots_in,
        const float* __restrict__ bk, const float* __restrict__ bv,
        unsigned short* __restrict__ Wk_b, unsigned short* __restrict__ Wq_b,
        unsigned short* __restrict__ Wv_b, unsigned short* __restrict__ Wih_b,
        unsigned short* __restrict__ Whh_b, unsigned short* __restrict__ W1T,
        unsigned short* __restrict__ W2T, unsigned short* __restrict__ slbf,
        float* __restrict__ wqbk, float* __restrict__ bvW) {
    __shared__ float tile[32][33];
    const int b = blockIdx.x;
    const int t = threadIdx.x;
    if (b < 1024) {                       // Wk convert [512][512]
        int idx = b * 256 + t; Wk_b[idx] = f2bf(Wk[idx]);
    } else if (b < 2048) {                // Wq convert
        int idx = (b - 1024) * 256 + t; Wq_b[idx] = f2bf(Wq[idx]);
    } else if (b < 3072) {                // Wv convert
        int idx = (b - 2048) * 256 + t; Wv_b[idx] = f2bf(Wv[idx]);
    } else if (b < 6144) {                // Wih convert [1536][512]
        int idx = (b - 3072) * 256 + t; Wih_b[idx] = f2bf(W_ih[idx]);
    } else if (b < 9216) {                // Whh convert
        int idx = (b - 6144) * 256 + t; Whh_b[idx] = f2bf(W_hh[idx]);
    } else if (b < 10240) {               // W1 [512][2048] -> W1T [2048][512]
        int i = b - 9216;
        tr32(W1, W1T, 512, 2048, (i & 63) * 32, (i >> 6) * 32, tile);
    } else if (b < 11264) {               // W2 [2048][512] -> W2T [512][2048]
        int i = b - 10240;
        tr32(W2, W2T, 2048, 512, (i & 15) * 32, (i >> 4) * 32, tile);
    } else if (b < 12032) {               // slbf: bf16 slots, 384-row padded
        int idx = (b - 11264) * 256 + t;
        int row = idx >> 9, d = idx & 511;
        int rr = row < 352 ? row : 351;
        slbf[idx] = f2bf(slots_in[(size_t)rr * 512 + d]);
    } else if (b < 12160) {               // wqbk[din] = Wq[din] . bk  (512 rows)
        int row = (b - 12032) * 4 + (t >> 6);
        rowdot512(Wq, bk, wqbk, row);
    } else {                              // bvW[n3] = W_ih[n3] . bv  (1536 rows)
        int row = (b - 12160) * 4 + (t >> 6);
        rowdot512(W_ih, bv, bvW, row);
    }
}

// ---------------- bf16 MFMA GEMM core: 64x64 tile, BK=64, swizzled LDS ----------------
// BMODE: 0 none, 1 +bias[n], 2 +bias[n]+coef[m]*bvW[n].  OUT_MODE: 0 fp32, 1 bf16, 2 both.
template<int BMODE, bool RELU, int OUT_MODE>
__device__ __forceinline__ void hgemm_core(
        const unsigned short* __restrict__ A, const unsigned short* __restrict__ Bt,
        const float* __restrict__ bias, const float* __restrict__ bvW,
        const float* __restrict__ coef, float* __restrict__ Cf,
        unsigned short* __restrict__ Cb, int m0, int n0, int N, int K,
        unsigned short* As, unsigned short* Bs) {
    const int t = threadIdx.x;
    const int lane = t & 63;
    const int w = t >> 6;
    const int wm = w >> 1, wn = w & 1;
    const int quad = lane >> 4;
    const int l15 = lane & 15;
    floatx4 acc[2][2];
    #pragma unroll
    for (int i = 0; i < 2; ++i)
        #pragma unroll
        for (int j = 0; j < 2; ++j)
            #pragma unroll
            for (int r = 0; r < 4; ++r) acc[i][j][r] = 0.0f;

    for (int k0 = 0; k0 < K; k0 += 64) {
        #pragma unroll
        for (int p = 0; p < 2; ++p) {
            const int s = p * 256 + t;
            const int row = s >> 3;
            const int c = (s & 7) ^ (row & 7);
            const int ldsoff = (s - lane) * 16;
            load_lds16(A  + (size_t)(m0 + row) * K + k0 + c * 8, (char*)As + ldsoff);
            load_lds16(Bt + (size_t)(n0 + row) * K + k0 + c * 8, (char*)Bs + ldsoff);
        }
        __builtin_amdgcn_s_waitcnt(0);
        __syncthreads();
        #pragma unroll
        for (int h = 0; h < 2; ++h) {
            bf16x8 af[2], bfr[2];
            #pragma unroll
            for (int i = 0; i < 2; ++i) {
                const int row = wm * 32 + i * 16 + l15;
                const int cp = ((h << 2) | quad) ^ (l15 & 7);
                af[i] = *(const bf16x8*)(As + row * 64 + cp * 8);
            }
            #pragma unroll
            for (int j = 0; j < 2; ++j) {
                const int row = wn * 32 + j * 16 + l15;
                const int cp = ((h << 2) | quad) ^ (l15 & 7);
                bfr[j] = *(const bf16x8*)(Bs + row * 64 + cp * 8);
            }
            #pragma unroll
            for (int i = 0; i < 2; ++i)
                #pragma unroll
                for (int j = 0; j < 2; ++j)
                    acc[i][j] = __builtin_amdgcn_mfma_f32_16x16x32_bf16(af[i], bfr[j], acc[i][j], 0, 0, 0);
        }
        __syncthreads();
    }
    #pragma unroll
    for (int j = 0; j < 2; ++j) {
        const int n = n0 + wn * 32 + j * 16 + l15;
        const float bb = (BMODE >= 1) ? bias[n] : 0.0f;
        const float bw = (BMODE == 2) ? bvW[n] : 0.0f;
        #pragma unroll
        for (int i = 0; i < 2; ++i) {
            #pragma unroll
            for (int r = 0; r < 4; ++r) {
                const int m = m0 + wm * 32 + i * 16 + quad * 4 + r;
                float v = acc[i][j][r] + bb;
                if (BMODE == 2) v += coef[m] * bw;
                if (RELU) v = fmaxf(v, 0.0f);
                if (OUT_MODE == 0 || OUT_MODE == 2) Cf[(size_t)m * N + n] = v;
                if (OUT_MODE == 1 || OUT_MODE == 2) Cb[(size_t)m * N + n] = f2bf(v);
            }
        }
    }
}

template<int BMODE, bool RELU, int OUT_MODE>
__global__ __launch_bounds__(256) void hgemm(
        const unsigned short* __restrict__ A, const unsigned short* __restrict__ Bt,
        const float* __restrict__ bias, float* __restrict__ Cf,
        unsigned short* __restrict__ Cb, int N, int K) {
    __shared__ unsigned short As[64 * 64];
    __shared__ unsigned short Bs[64 * 64];
    hgemm_core<BMODE, RELU, OUT_MODE>(A, Bt, bias, nullptr, nullptr, Cf, Cb,
                                      blockIdx.y * 64, blockIdx.x * 64, N, K, As, Bs);
}

// one-time weight-composition GEMMs: z=0 WqkT = Wk@Wq^T ; z=1 Wc = Wih@Wv^T
__global__ __launch_bounds__(256) void prep_gemms(
        const unsigned short* __restrict__ Wk_b, const unsigned short* __restrict__ Wq_b,
        const unsigned short* __restrict__ Wih_b, const unsigned short* __restrict__ Wv_b,
        unsigned short* __restrict__ WqkT, unsigned short* __restrict__ Wc) {
    __shared__ unsigned short As[64 * 64];
    __shared__ unsigned short Bs[64 * 64];
    if (blockIdx.z == 0) {
        if (blockIdx.y >= 8) return;
        hgemm_core<0, false, 1>(Wk_b, Wq_b, nullptr, nullptr, nullptr, nullptr, WqkT,
                                blockIdx.y * 64, blockIdx.x * 64, 512, 512, As, Bs);
    } else {
        hgemm_core<0, false, 1>(Wih_b, Wv_b, nullptr, nullptr, nullptr, nullptr, Wc,
                                blockIdx.y * 64, blockIdx.x * 64, 512, 512, As, Bs);
    }
}

// gi and gh in one launch (blockIdx.z selects)
__global__ __launch_bounds__(256) void gru_gemm(
        const unsigned short* __restrict__ Pn, const unsigned short* __restrict__ slbf,
        const unsigned short* __restrict__ Wc, const unsigned short* __restrict__ Whh,
        const float* __restrict__ bih, const float* __restrict__ bhh,
        const float* __restrict__ bvW, const float* __restrict__ coef,
        float* __restrict__ gi, float* __restrict__ gh) {
    __shared__ unsigned short As[64 * 64];
    __shared__ unsigned short Bs[64 * 64];
    if (blockIdx.z == 0)
        hgemm_core<2, false, 0>(Pn, Wc, bih, bvW, coef, gi, nullptr,
                                blockIdx.y * 64, blockIdx.x * 64, 1536, 512, As, Bs);
    else
        hgemm_core<1, false, 0>(slbf, Whh, bhh, nullptr, nullptr, gh, nullptr,
                                blockIdx.y * 64, blockIdx.x * 64, 1536, 512, As, Bs);
}

// ---------------- fused inverted attention over xln (k,v never materialized) ----------------
__global__ __launch_bounds__(256) void attn_kernel(
        const float* __restrict__ qp, const unsigned short* __restrict__ xln,
        const float* __restrict__ cbuf,
        float* __restrict__ Up, float* __restrict__ rsp) {
    const int b = blockIdx.y;
    const int chunk = blockIdx.x;
    const int w = threadIdx.x >> 6, lane = threadIdx.x & 63;
    const int d0 = lane * 8;
    const int NPC = 4096 / NCHUNK;

    float qr[11][8];
    float cr[11];
    {
        const float* qb = qp + (size_t)b * 11 * 512 + d0;
        #pragma unroll
        for (int s = 0; s < 11; ++s) {
            float4 q0 = *(const float4*)(qb + s * 512);
            float4 q1 = *(const float4*)(qb + s * 512 + 4);
            qr[s][0] = q0.x; qr[s][1] = q0.y; qr[s][2] = q0.z; qr[s][3] = q0.w;
            qr[s][4] = q1.x; qr[s][5] = q1.y; qr[s][6] = q1.z; qr[s][7] = q1.w;
            cr[s] = cbuf[b * 11 + s];
        }
    }
    float U[11][8];
    float rs[11];
    #pragma unroll
    for (int s = 0; s < 11; ++s) {
        rs[s] = 0.f;
        #pragma unroll
        for (int j = 0; j < 8; ++j) U[s][j] = 0.f;
    }

    const size_t base = ((size_t)b * 4096 + (size_t)chunk * NPC) * 512 + d0;
    for (int nn = w; nn < NPC; nn += 4) {
        const unsigned short* kp = xln + base + (size_t)nn * 512;
        uint4 kr = *(const uint4*)kp;
        float kf[8];
        kf[0] = __uint_as_float(kr.x << 16); kf[1] = __uint_as_float(kr.x & 0xffff0000u);
        kf[2] = __uint_as_float(kr.y << 16); kf[3] = __uint_as_float(kr.y & 0xffff0000u);
        kf[4] = __uint_as_float(kr.z << 16); kf[5] = __uint_as_float(kr.z & 0xffff0000u);
        kf[6] = __uint_as_float(kr.w << 16); kf[7] = __uint_as_float(kr.w & 0xffff0000u);
        float l[11];
        #pragma unroll
        for (int s = 0; s < 11; ++s) {
            float p = kf[0] * qr[s][0];
            #pragma unroll
            for (int j = 1; j < 8; ++j) p = fmaf(kf[j], qr[s][j], p);
            l[s] = p;
        }
        #pragma unroll
        for (int off = 32; off > 0; off >>= 1)
            #pragma unroll
            for (int s = 0; s < 11; ++s) l[s] += __shfl_xor(l[s], off, 64);
        #pragma unroll
        for (int s = 0; s < 11; ++s) l[s] += cr[s];
        float mx = l[0];
        #pragma unroll
        for (int s = 1; s < 11; ++s) mx = fmaxf(mx, l[s]);
        float se = 0.f;
        #pragma unroll
        for (int s = 0; s < 11; ++s) { l[s] = __expf(l[s] - mx); se += l[s]; }
        float inv = 1.0f / se;
        #pragma unroll
        for (int s = 0; s < 11; ++s) {
            float a = l[s] * inv;
            rs[s] += a;
            #pragma unroll
            for (int j = 0; j < 8; ++j) U[s][j] = fmaf(a, kf[j], U[s][j]);
        }
    }
    __shared__ float Us[11 * 512];
    __shared__ float rss[11];
    for (int ph = 0; ph < 4; ++ph) {
        if (w == ph) {
            #pragma unroll
            for (int s = 0; s < 11; ++s) {
                #pragma unroll
                for (int j = 0; j < 8; ++j) {
                    if (ph == 0) Us[s * 512 + d0 + j] = U[s][j];
                    else         Us[s * 512 + d0 + j] += U[s][j];
                }
            }
            if (lane == 0) {
                #pragma unroll
                for (int s = 0; s < 11; ++s) {
                    if (ph == 0) rss[s] = rs[s]; else rss[s] += rs[s];
                }
            }
        }
        __syncthreads();
    }
    float* up = Up + ((size_t)b * NCHUNK + chunk) * 11 * 512;
    for (int idx = threadIdx.x; idx < 11 * 512; idx += 256) up[idx] = Us[idx];
    if (threadIdx.x < 11) rsp[((size_t)b * NCHUNK + chunk) * 11 + threadIdx.x] = rss[threadIdx.x];
}

// ------------- reduce partials -> Pn(bf16) = U/(rs+eps), coef = rs/(rs+eps) -------------
__global__ __launch_bounds__(256) void attn_reduce(
        const float* __restrict__ Up, const float* __restrict__ rsp,
        unsigned short* __restrict__ Pn, float* __restrict__ coef) {
    const int bs = blockIdx.x;  // grid 384 (pad rows -> zeros)
    if (bs >= 352) {
        for (int d = threadIdx.x; d < 512; d += 256) Pn[(size_t)bs * 512 + d] = 0;
        if (threadIdx.x == 0) coef[bs] = 0.0f;
        return;
    }
    const int b = bs / 11, s = bs - b * 11;
    float rsum = 0.0f;
    #pragma unroll
    for (int c = 0; c < NCHUNK; ++c) rsum += rsp[((size_t)b * NCHUNK + c) * 11 + s];
    const float inv = 1.0f / (rsum + ATTN_EPS);
    if (threadIdx.x == 0) coef[bs] = rsum * inv;
    for (int d = threadIdx.x; d < 512; d += 256) {
        float acc = 0.f;
        #pragma unroll
        for (int c = 0; c < NCHUNK; ++c) acc += Up[(((size_t)b * NCHUNK + c) * 11 + s) * 512 + d];
        Pn[(size_t)bs * 512 + d] = f2bf(acc * inv);
    }
}

// ---------------- fused GRU + MLP-LayerNorm: gi,gh,slots -> mln(bf16) ----------------
__global__ __launch_bounds__(256) void gru_ln(
        const float* __restrict__ gi, const float* __restrict__ gh,
        const float* __restrict__ slots, const float* __restrict__ g,
        const float* __restrict__ b, unsigned short* __restrict__ mln) {
    int row = blockIdx.x * 4 + (threadIdx.x >> 6);
    int lane = threadIdx.x & 63;
    unsigned short* orow = mln + (size_t)row * 512;
    if (row >= 352) {
        ushort4v z; z.x = z.y = z.z = z.w = 0;
        *(ushort4v*)(orow + lane * 4) = z;
        *(ushort4v*)(orow + 256 + lane * 4) = z;
        return;
    }
    const float4* gir = (const float4*)(gi + (size_t)row * 1536);
    const float4* ghr = (const float4*)(gh + (size_t)row * 1536);
    const float4* sr  = (const float4*)(slots + (size_t)row * 512);
    float v[8];
    #pragma unroll
    for (int half = 0; half < 2; ++half) {
        int o = half * 64 + lane;
        float4 ir = gir[o], iz = gir[128 + o], in_ = gir[256 + o];
        float4 hr = ghr[o], hz = ghr[128 + o], hn = ghr[256 + o];
        float4 sv = sr[o];
        float rr[4], zz[4], nn[4];
        rr[0] = 1.f / (1.f + __expf(-(ir.x + hr.x)));
        rr[1] = 1.f / (1.f + __expf(-(ir.y + hr.y)));
        rr[2] = 1.f / (1.f + __expf(-(ir.z + hr.z)));
        rr[3] = 1.f / (1.f + __expf(-(ir.w + hr.w)));
        zz[0] = 1.f / (1.f + __expf(-(iz.x + hz.x)));
        zz[1] = 1.f / (1.f + __expf(-(iz.y + hz.y)));
        zz[2] = 1.f / (1.f + __expf(-(iz.z + hz.z)));
        zz[3] = 1.f / (1.f + __expf(-(iz.w + hz.w)));
        nn[0] = tanhf(in_.x + rr[0] * hn.x);
        nn[1] = tanhf(in_.y + rr[1] * hn.y);
        nn[2] = tanhf(in_.z + rr[2] * hn.z);
        nn[3] = tanhf(in_.w + rr[3] * hn.w);
        v[half * 4 + 0] = (1.f - zz[0]) * nn[0] + zz[0] * sv.x;
        v[half * 4 + 1] = (1.f - zz[1]) * nn[1] + zz[1] * sv.y;
        v[half * 4 + 2] = (1.f - zz[2]) * nn[2] + zz[2] * sv.z;
        v[half * 4 + 3] = (1.f - zz[3]) * nn[3] + zz[3] * sv.w;
    }
    float s = 0.f, ss = 0.f;
    #pragma unroll
    for (int j = 0; j < 8; ++j) { s += v[j]; ss += v[j] * v[j]; }
    #pragma unroll
    for (int off = 32; off > 0; off >>= 1) {
        s  += __shfl_xor(s, off, 64);
        ss += __shfl_xor(ss, off, 64);
    }
    float mu = s * (1.0f / 512.0f);
    float var = ss * (1.0f / 512.0f) - mu * mu;
    float rstd = rsqrtf(var + LN_EPS);
    float4 g0 = ((const float4*)g)[lane], g1 = ((const float4*)g)[lane + 64];
    float4 b0 = ((const float4*)b)[lane], b1 = ((const float4*)b)[lane + 64];
    ushort4v o0, o1;
    o0.x = f2bf((v[0] - mu) * rstd * g0.x + b0.x);
    o0.y = f2bf((v[1] - mu) * rstd * g0.y + b0.y);
    o0.z = f2bf((v[2] - mu) * rstd * g0.z + b0.z);
    o0.w = f2bf((v[3] - mu) * rstd * g0.w + b0.w);
    o1.x = f2bf((v[4] - mu) * rstd * g1.x + b1.x);
    o1.y = f2bf((v[5] - mu) * rstd * g1.y + b1.y);
    o1.z = f2bf((v[6] - mu) * rstd * g1.z + b1.z);
    o1.w = f2bf((v[7] - mu) * rstd * g1.w + b1.w);
    *(ushort4v*)(orow + lane * 4) = o0;
    *(ushort4v*)(orow + 256 + lane * 4) = o1;
}

extern "C" void kernel_launch(void* const* d_in, const int* in_sizes, int n_in,
                              void* d_out, int out_size, void* d_ws, size_t ws_size,
                              hipStream_t stream) {
    const float* slots_in = (const float*)d_in[0];
    const float* inputs   = (const float*)d_in[1];
    const float* ln_in_g  = (const float*)d_in[2];
    const float* ln_in_b  = (const float*)d_in[3];
    const float* Wk  = (const float*)d_in[4];
    const float* bk  = (const float*)d_in[5];
    const float* Wv  = (const float*)d_in[6];
    const float* bv  = (const float*)d_in[7];
    const float* ln_q_g = (const float*)d_in[8];
    const float* ln_q_b = (const float*)d_in[9];
    const float* Wq  = (const float*)d_in[10];
    const float* W_ih = (const float*)d_in[11];
    const float* b_ih = (const float*)d_in[12];
    const float* W_hh = (const float*)d_in[13];
    const float* b_hh = (const float*)d_in[14];
    const float* ln_m_g = (const float*)d_in[15];
    const float* ln_m_b = (const float*)d_in[16];
    const float* W1 = (const float*)d_in[17];
    const float* b1 = (const float*)d_in[18];
    const float* W2 = (const float*)d_in[19];
    const float* b2 = (const float*)d_in[20];

    char* p = (char*)d_ws;
    auto alloc = [&](size_t bytes) { char* r = p; p += (bytes + 255) & ~(size_t)255; return r; };
    unsigned short* xln   = (unsigned short*)alloc(131072ull * 512 * 2);
    unsigned short* Wk_b  = (unsigned short*)alloc(512ull * 512 * 2);
    unsigned short* Wq_b  = (unsigned short*)alloc(512ull * 512 * 2);
    unsigned short* Wv_b  = (unsigned short*)alloc(512ull * 512 * 2);
    unsigned short* Wih_b = (unsigned short*)alloc(1536ull * 512 * 2);
    unsigned short* Whh_b = (unsigned short*)alloc(1536ull * 512 * 2);
    unsigned short* WqkT  = (unsigned short*)alloc(512ull * 512 * 2);
    unsigned short* Wc    = (unsigned short*)alloc(1536ull * 512 * 2);
    unsigned short* W1T   = (unsigned short*)alloc(2048ull * 512 * 2);
    unsigned short* W2T   = (unsigned short*)alloc(512ull * 2048 * 2);
    unsigned short* slq   = (unsigned short*)alloc(384ull * 512 * 2);
    unsigned short* mln   = (unsigned short*)alloc(384ull * 512 * 2);
    unsigned short* Pn    = (unsigned short*)alloc(384ull * 512 * 2);
    unsigned short* slbf  = (unsigned short*)alloc(384ull * 512 * 2);
    unsigned short* h1    = (unsigned short*)alloc(384ull * 2048 * 2);
    float* qp    = (float*)alloc(384ull * 512 * 4);
    float* slots = (float*)alloc(384ull * 512 * 4);
    float* gi    = (float*)alloc(384ull * 1536 * 4);
    float* gh    = (float*)alloc(384ull * 1536 * 4);
    float* Up    = (float*)alloc((size_t)32 * NCHUNK * 11 * 512 * 4);
    float* rsp   = (float*)alloc((size_t)32 * NCHUNK * 11 * 4);
    float* wqbk  = (float*)alloc(512 * 4);
    float* bvW   = (float*)alloc(1536 * 4);
    float* cbuf  = (float*)alloc(384 * 4);
    float* coef  = (float*)alloc(384 * 4);

    // ---- one-time prep ----
    ln512_kernel<true, false><<<dim3(32768), 256, 0, stream>>>(
        inputs, ln_in_g, ln_in_b, xln, 131072, 131072, 1.0f, nullptr, nullptr);
    prep_all<<<dim3(12544), 256, 0, stream>>>(
        Wk, Wq, Wv, W_ih, W_hh, W1, W2, slots_in, bk, bv,
        Wk_b, Wq_b, Wv_b, Wih_b, Whh_b, W1T, W2T, slbf, wqbk, bvW);
    prep_gemms<<<dim3(8, 24, 2), 256, 0, stream>>>(Wk_b, Wq_b, Wih_b, Wv_b, WqkT, Wc);
    hipMemcpyAsync(slots, slots_in, 352ull * 512 * 4, hipMemcpyDeviceToDevice, stream);

    const float qscale = 0.044194173824159216f;  // 1/sqrt(512)
    for (int it = 0; it < 3; ++it) {
        ln512_kernel<true, true><<<dim3(96), 256, 0, stream>>>(
            slots, ln_q_g, ln_q_b, slq, 384, 352, qscale, wqbk, cbuf);
        hgemm<0, false, 0><<<dim3(8, 6), 256, 0, stream>>>(slq, WqkT, nullptr, qp, nullptr, 512, 512);
        attn_kernel<<<dim3(NCHUNK, 32), 256, 0, stream>>>(qp, xln, cbuf, Up, rsp);
        attn_reduce<<<dim3(384), 256, 0, stream>>>(Up, rsp, Pn, coef);
        gru_gemm<<<dim3(24, 6, 2), 256, 0, stream>>>(Pn, slbf, Wc, Whh_b, b_ih, b_hh, bvW, coef, gi, gh);
        gru_ln<<<dim3(96), 256, 0, stream>>>(gi, gh, slots, ln_m_g, ln_m_b, mln);
        hgemm<1, true, 1><<<dim3(32, 6), 256, 0, stream>>>(mln, W1T, b1, nullptr, h1, 2048, 512);
        hgemm<1, false, 2><<<dim3(8, 6), 256, 0, stream>>>(h1, W2T, b2, slots, slbf, 512, 2048);
    }
    hipMemcpyAsync(d_out, slots, (size_t)out_size * 4, hipMemcpyDeviceToDevice, stream);
}